// Round 1
// baseline (313.143 us; speedup 1.0000x reference)
//
#include <hip/hip_runtime.h>

#define Bn 8
#define Tn 4096
#define Dn 256
#define Mn (Bn*Tn)           // 32768

typedef short bf16x8 __attribute__((ext_vector_type(8)));
typedef float f32x4 __attribute__((ext_vector_type(4)));

__device__ __forceinline__ unsigned short f2bf(float f) {
    union { float f; unsigned int u; } v; v.f = f;
    unsigned int r = v.u + 0x7fffu + ((v.u >> 16) & 1u);
    return (unsigned short)(r >> 16);
}

// ---------------- cast x (f32 -> bf16), 8 elems/thread ----------------
__global__ void __launch_bounds__(256) cast_x_kernel(const float* __restrict__ x,
                                                     unsigned short* __restrict__ xb) {
    size_t i = (size_t)blockIdx.x * 256 + threadIdx.x;   // one per 8 elements
    const float4* p = reinterpret_cast<const float4*>(x) + i * 2;
    float4 a = p[0], b = p[1];
    union { unsigned short u[8]; uint4 v; } o;
    o.u[0]=f2bf(a.x); o.u[1]=f2bf(a.y); o.u[2]=f2bf(a.z); o.u[3]=f2bf(a.w);
    o.u[4]=f2bf(b.x); o.u[5]=f2bf(b.y); o.u[6]=f2bf(b.z); o.u[7]=f2bf(b.w);
    reinterpret_cast<uint4*>(xb)[i] = o.v;
}

// ---------------- W transpose+cast: Wt[h][n][k] = W_h[k][n] ----------------
__global__ void __launch_bounds__(256) wt_kernel(const float* __restrict__ wq,
                                                 const float* __restrict__ wk,
                                                 const float* __restrict__ wv,
                                                 unsigned short* __restrict__ wt) {
    int idx = blockIdx.x * 256 + threadIdx.x;     // 0 .. 3*65536-1
    int h = idx >> 16; int r = idx & 65535;
    int k = r >> 8, n = r & 255;
    const float* src = (h == 0) ? wq : (h == 1) ? wk : wv;
    wt[h * 65536 + n * 256 + k] = f2bf(src[k * 256 + n]);
}

// ---------------- projection GEMM: out[h] = xb @ W_h  (bf16 out) ----------------
// block: 64 rows x 256 cols, 4 waves x 16 rows, K=256 in 8 steps of 32
__global__ void __launch_bounds__(256, 2) proj_kernel(const unsigned short* __restrict__ xb,
                                                      const unsigned short* __restrict__ wt,
                                                      unsigned short* __restrict__ qkv) {
    __shared__ unsigned short wlds[256 * 40];   // Wt slice [256][32] padded to 40
    int h = blockIdx.y;
    const unsigned short* wth = wt + h * 65536;
    unsigned short* out = qkv + (size_t)h * Mn * Dn;
    int m0 = blockIdx.x * 64;
    int tid = threadIdx.x;
    int w = tid >> 6, lane = tid & 63;
    int c = lane & 15, g = lane >> 4;
    size_t arow = (size_t)(m0 + w * 16 + c);

    const f32x4 fz = {0.f, 0.f, 0.f, 0.f};
    f32x4 acc[16];
#pragma unroll
    for (int n = 0; n < 16; n++) acc[n] = fz;

    for (int kk = 0; kk < 8; kk++) {
        __syncthreads();
#pragma unroll
        for (int p = 0; p < 4; p++) {
            int idx = p * 256 + tid;
            int r = idx >> 2, ch = idx & 3;
            bf16x8 v = *(const bf16x8*)(wth + r * 256 + kk * 32 + ch * 8);
            *(bf16x8*)(&wlds[r * 40 + ch * 8]) = v;
        }
        __syncthreads();
        bf16x8 af = *(const bf16x8*)(xb + arow * Dn + kk * 32 + g * 8);
#pragma unroll
        for (int n = 0; n < 16; n++) {
            bf16x8 bfv = *(const bf16x8*)(&wlds[(n * 16 + c) * 40 + g * 8]);
            acc[n] = __builtin_amdgcn_mfma_f32_16x16x32_bf16(af, bfv, acc[n], 0, 0, 0);
        }
    }
    size_t orow0 = (size_t)(m0 + w * 16 + g * 4);
#pragma unroll
    for (int n = 0; n < 16; n++)
#pragma unroll
        for (int r = 0; r < 4; r++)
            out[(orow0 + r) * Dn + n * 16 + c] = f2bf(acc[n][r]);
}

// ---------------- causal flash attention ----------------
// 512 blocks: k<256 -> (b=k&7, qt=k>>3); k>=256 -> qt = 63 - ((k-256)>>3)  (work balance)
// 4 waves x 16 q-rows, KVBLK=32, D=256
__global__ void __launch_bounds__(256, 2) attn_kernel(const unsigned short* __restrict__ qkv,
                                                      float* __restrict__ outp) {
    __shared__ unsigned short klds[32 * 256];   // XOR-swizzled
    __shared__ unsigned short vtlds[256 * 40];  // V transposed [feat][kv], padded
    __shared__ float plds[4][16 * 36];          // per-wave P, padded stride 36

    int blk = blockIdx.x;
    int half = blk >> 8, rr = blk & 255;
    int b = rr & 7;
    int qt = rr >> 3; if (half) qt = 63 - qt;
    int q0 = qt * 64;

    int tid = threadIdx.x, w = tid >> 6, lane = tid & 63;
    int c = lane & 15, g = lane >> 4;

    const unsigned short* Qg = qkv;
    const unsigned short* Kg = qkv + (size_t)Mn * Dn;
    const unsigned short* Vg = qkv + (size_t)2 * Mn * Dn;

    int qrow = q0 + w * 16;                       // wave's first q row (in batch)
    size_t qbase = (size_t)b * Tn + qrow;

    bf16x8 qf[8];
#pragma unroll
    for (int kk = 0; kk < 8; kk++)
        qf[kk] = *(const bf16x8*)(Qg + (qbase + c) * Dn + kk * 32 + g * 8);

    const f32x4 fz = {0.f, 0.f, 0.f, 0.f};
    f32x4 o[16];
#pragma unroll
    for (int n = 0; n < 16; n++) o[n] = fz;
    float m_r[4] = {-INFINITY, -INFINITY, -INFINITY, -INFINITY};
    float l_r[4] = {0.f, 0.f, 0.f, 0.f};

    int nt = qt * 2 + 2;
    for (int t = 0; t < nt; t++) {
        int kv0 = t * 32;
        __syncthreads();   // prior tile's LDS reads complete
        // ---- stage K tile [32][256], swizzled ----
#pragma unroll
        for (int p = 0; p < 4; p++) {
            int idx = p * 256 + tid;
            int r = idx >> 5, ch = idx & 31;
            bf16x8 v = *(const bf16x8*)(Kg + ((size_t)b * Tn + kv0 + r) * Dn + ch * 8);
            int baddr = (r * 512 + ch * 16) ^ ((r & 7) << 4);
            *(bf16x8*)((char*)klds + baddr) = v;
        }
        // ---- stage V tile transposed: vtlds[f][kv] ----
#pragma unroll
        for (int p = 0; p < 4; p++) {
            int idx = p * 256 + tid;
            int kv = idx & 31, fc = idx >> 5;
            union { bf16x8 v; unsigned short u[8]; } uv;
            uv.v = *(const bf16x8*)(Vg + ((size_t)b * Tn + kv0 + kv) * Dn + fc * 8);
#pragma unroll
            for (int i = 0; i < 8; i++)
                vtlds[(fc * 8 + i) * 40 + kv] = uv.u[i];
        }
        __syncthreads();
        // ---- S = Q K^T ----
        f32x4 s[2]; s[0] = fz; s[1] = fz;
#pragma unroll
        for (int n = 0; n < 2; n++) {
            int r = n * 16 + c;
#pragma unroll
            for (int kk = 0; kk < 8; kk++) {
                int baddr = (r * 512 + kk * 64 + g * 16) ^ ((r & 7) << 4);
                bf16x8 kf = *(const bf16x8*)((char*)klds + baddr);
                s[n] = __builtin_amdgcn_mfma_f32_16x16x32_bf16(qf[kk], kf, s[n], 0, 0, 0);
            }
        }
        // ---- scale + causal mask ----
        float sv[2][4];
#pragma unroll
        for (int n = 0; n < 2; n++)
#pragma unroll
            for (int r = 0; r < 4; r++) {
                float v = s[n][r] * 0.0625f;
                int qg = qrow + g * 4 + r;
                int kvg = kv0 + n * 16 + c;
                sv[n][r] = (kvg <= qg) ? v : -INFINITY;
            }
        // ---- online softmax (per reg = per q-row) ----
        float alpha[4];
#pragma unroll
        for (int r = 0; r < 4; r++) {
            float mx = fmaxf(sv[0][r], sv[1][r]);
#pragma unroll
            for (int off = 1; off < 16; off <<= 1) mx = fmaxf(mx, __shfl_xor(mx, off));
            float mn = fmaxf(m_r[r], mx);
            alpha[r] = __expf(m_r[r] - mn);
            float p0 = __expf(sv[0][r] - mn);
            float p1 = __expf(sv[1][r] - mn);
            float ps = p0 + p1;
#pragma unroll
            for (int off = 1; off < 16; off <<= 1) ps += __shfl_xor(ps, off);
            l_r[r] = l_r[r] * alpha[r] + ps;
            m_r[r] = mn;
            plds[w][(g * 4 + r) * 36 + c] = p0;
            plds[w][(g * 4 + r) * 36 + 16 + c] = p1;
        }
#pragma unroll
        for (int n = 0; n < 16; n++) {
            f32x4 t4 = o[n];
            t4[0] *= alpha[0]; t4[1] *= alpha[1]; t4[2] *= alpha[2]; t4[3] *= alpha[3];
            o[n] = t4;
        }
        __syncthreads();   // P visible (and cheap global barrier for LDS ordering)
        // ---- P fragment (A-layout) ----
        f32x4 pa = *(const f32x4*)(&plds[w][c * 36 + g * 8]);
        f32x4 pb = *(const f32x4*)(&plds[w][c * 36 + g * 8 + 4]);
        union { unsigned short u[8]; bf16x8 v; } pf;
        pf.u[0] = f2bf(pa[0]); pf.u[1] = f2bf(pa[1]); pf.u[2] = f2bf(pa[2]); pf.u[3] = f2bf(pa[3]);
        pf.u[4] = f2bf(pb[0]); pf.u[5] = f2bf(pb[1]); pf.u[6] = f2bf(pb[2]); pf.u[7] = f2bf(pb[3]);
        // ---- O += P V ----
#pragma unroll
        for (int n = 0; n < 16; n++) {
            bf16x8 vf = *(const bf16x8*)(&vtlds[(n * 16 + c) * 40 + g * 8]);
            o[n] = __builtin_amdgcn_mfma_f32_16x16x32_bf16(pf.v, vf, o[n], 0, 0, 0);
        }
    }
    // ---- epilogue ----
    float inv[4] = {1.f / l_r[0], 1.f / l_r[1], 1.f / l_r[2], 1.f / l_r[3]};
    size_t obase = ((size_t)b * Tn + qrow + g * 4) * Dn;
#pragma unroll
    for (int n = 0; n < 16; n++)
#pragma unroll
        for (int r = 0; r < 4; r++)
            outp[obase + (size_t)r * Dn + n * 16 + c] = o[n][r] * inv[r];
}

extern "C" void kernel_launch(void* const* d_in, const int* in_sizes, int n_in,
                              void* d_out, int out_size, void* d_ws, size_t ws_size,
                              hipStream_t stream) {
    (void)in_sizes; (void)n_in; (void)out_size; (void)ws_size;
    const float* x  = (const float*)d_in[0];
    const float* wk = (const float*)d_in[1];
    const float* wq = (const float*)d_in[2];
    const float* wv = (const float*)d_in[3];
    float* outp = (float*)d_out;

    char* ws = (char*)d_ws;
    unsigned short* xb  = (unsigned short*)ws;                 // 16 MB
    unsigned short* wt  = (unsigned short*)(ws + 16777216);    // 384 KB, order: [Wq, Wk, Wv]
    unsigned short* qkv = (unsigned short*)(ws + 17170432);    // 48 MB: [Q, K, V] bf16

    cast_x_kernel<<<Mn * Dn / 8 / 256, 256, 0, stream>>>(x, xb);
    wt_kernel<<<3 * 65536 / 256, 256, 0, stream>>>(wq, wk, wv, wt);
    proj_kernel<<<dim3(Mn / 64, 3), 256, 0, stream>>>(xb, wt, qkv);
    attn_kernel<<<512, 256, 0, stream>>>(qkv, outp);
}